// Round 10
// baseline (4696.855 us; speedup 1.0000x reference)
//
#include <hip/hip_runtime.h>
#include <math.h>

#define Bb   16
#define Tt   2048
#define Dd   1024
#define NL   4
#define MTOT (Bb * Tt)   // 32768

typedef float f32x4 __attribute__((ext_vector_type(4)));
typedef short bf16x8 __attribute__((ext_vector_type(8)));

// ---------------------------------------------------------------------------
__device__ __forceinline__ unsigned short f2bf_rne(float x) {
    unsigned u = __float_as_uint(x);
    u += 0x7fffu + ((u >> 16) & 1u);
    return (unsigned short)(u >> 16);
}
__device__ __forceinline__ float bf2f(unsigned short h) {
    return __uint_as_float(((unsigned)h) << 16);
}
__device__ __forceinline__ float rec2(unsigned short h, unsigned short l) {
    return bf2f(h) + bf2f(l);
}
__device__ __forceinline__ float gelu_tanh(float x) {
    float x3 = x * x * x;
    float u  = 0.7978845608028654f * (x + 0.044715f * x3);
    return 0.5f * x * (1.0f + tanhf(u));
}
// async 16B global -> LDS (HW: wave-uniform LDS base + lane*16; global addr per-lane)
__device__ __forceinline__ void dma16(const void* g, void* l) {
    __builtin_amdgcn_global_load_lds(
        (const __attribute__((address_space(1))) unsigned int*)g,
        (__attribute__((address_space(3))) unsigned int*)l, 16, 0, 0);
}

// ---------------------------------------------------------------------------
// Split a [1024,1024] fp32 matrix (row-major [k][n]) into bf16 hi/lo with
// k-tiled, slot-swizzled layout (proven R6 B-path):
//   fragment (n, kt, sl) -> shorts offset ((kt*1024+n)*4 + (sl^((n>>1)&3)))*8
// ---------------------------------------------------------------------------
__global__ __launch_bounds__(256)
void split_bt(const float* __restrict__ B, short* __restrict__ ht,
              short* __restrict__ lt)
{
    __shared__ float tile[32][33];
    const int t  = threadIdx.x;
    const int r  = t >> 3;          // 0..31
    const int c  = (t & 7) * 4;     // 0,4,...,28
    const int kb = blockIdx.y * 32; // kt = blockIdx.y
    const int nb = blockIdx.x * 32;
    float4 v = *reinterpret_cast<const float4*>(
        &B[(size_t)(kb + r) * Dd + nb + c]);
    tile[r][c + 0] = v.x; tile[r][c + 1] = v.y;
    tile[r][c + 2] = v.z; tile[r][c + 3] = v.w;
    __syncthreads();
    unsigned h[4], lo[4];
#pragma unroll
    for (int q = 0; q < 4; ++q) {
        float f = tile[c + q][r];           // B[kb+c+q][nb+r]
        unsigned short hh = f2bf_rne(f);
        float rem = f - bf2f(hh);
        h[q]  = hh;
        lo[q] = f2bf_rne(rem);
    }
    uint2 hw, lw;
    hw.x = h[0]  | (h[1]  << 16); hw.y = h[2]  | (h[3]  << 16);
    lw.x = lo[0] | (lo[1] << 16); lw.y = lo[2] | (lo[3] << 16);
    const int n = nb + r;
    const int s = (c >> 3) ^ ((n >> 1) & 3);   // swizzled slot
    size_t off = ((size_t)(blockIdx.y * 1024 + n) * 4 + s) * 8 + (c & 4);
    *reinterpret_cast<uint2*>(&ht[off]) = hw;
    *reinterpret_cast<uint2*>(&lt[off]) = lw;
}

// ---------------------------------------------------------------------------
// Unified split-precision MFMA GEMM (fp32 via 3 bf16 MFMAs).
// R6-proven structure: tile 128xNT, BK=32, 256 thr = 4 waves (2x2), two
// barriers per k-tile, 2 blocks/CU for cross-block latency hiding.
// ADMA=1: A comes as (hi,lo) bf16 planes, staged by pure global_load_lds DMA
//         with per-lane swizzled SOURCE addresses (LDS linear); masked scan
//         rows read a zero page.
// ADMA=0: A is fp32, staged via reg->convert->ds_write (xp / squarings).
// OSPLIT=1: epilogue writes C as (hi,lo) bf16 planes (state format).
// OSPLIT=0: epilogue writes fp32 (power matrices).
// MODE 0: C = A@B (+bias);  MODE 1: C[t] = S[t] + (t%Tt>=m ? A[t-m]@B : 0);
// MODE 2: rows [tstart,tstart+128) per batch: C[r] = S[r] + A[r-128]@B.
// BN=1:  emit per-(m-tile, column) partial sum/sumsq (reuses LDS at end).
// ---------------------------------------------------------------------------
template<int MODE, int BN, int NT, int ADMA, int OSPLIT>
__global__ __launch_bounds__(256, 2)
void mfma_gemm(const float* __restrict__ Af,
               const short* __restrict__ Ah, const short* __restrict__ Al,
               const short* __restrict__ Bth, const short* __restrict__ Btl,
               const float* __restrict__ bias,
               const short* __restrict__ Sh, const short* __restrict__ Sl,
               float* __restrict__ Cf,
               short* __restrict__ Ch, short* __restrict__ Cl,
               float* __restrict__ psum, float* __restrict__ psq,
               const short* __restrict__ zp,
               int m, int tstart)
{
    constexpr int NJ    = NT / 32;            // j-fragments per wave
    constexpr int APL   = ADMA ? 4096 : 5120; // shorts per A plane
    constexpr int BBASE = 2 * APL;
    constexpr int BPL   = NT * 32;            // shorts per B plane
    __shared__ __align__(16) short lds[BBASE + 2 * BPL];

    const int tid  = threadIdx.x;
    const int lane = tid & 63;
    const int w    = tid >> 6;
    const int n0   = blockIdx.x * NT;
    const int m0g  = (MODE == 2) ? (blockIdx.y * Tt + tstart)
                                 : (blockIdx.y * 128);
    const int wm0  = (w >> 1) * 64;
    const int wn0  = (w & 1) * (NT / 2);
    const int ln   = lane & 15;

    // ---- convert-path staging map (ADMA=0) ----
    const int ar = tid >> 3;
    const int ac = (tid & 7) * 4;
    int  arow_src[4]; bool avalid[4];
    if (!ADMA) {
#pragma unroll
        for (int p = 0; p < 4; ++p) {
            int rg = m0g + p * 32 + ar;
            bool v = true;
            if (MODE == 1) v = ((rg & (Tt - 1)) >= m);
            avalid[p]   = v;
            arow_src[p] = (MODE >= 1 && v) ? (rg - m) : rg;
        }
    }
    // ---- DMA-path staging map (ADMA=1): 2 rounds x (hi,lo) ----
    const short* ah_src[2];
    const short* al_src[2];
    int adst[2];
    if (ADMA) {
#pragma unroll
        for (int r = 0; r < 2; ++r) {
            int rl = (r * 4 + w) * 16 + (lane >> 2);   // local row 0..127
            int rg = m0g + rl;
            bool v = true;
            if (MODE == 1) v = ((rg & (Tt - 1)) >= m);
            int srow = (MODE >= 1) ? (rg - m) : rg;
            int slot = ((lane & 3) ^ ((rl >> 1) & 3)) << 3;  // shorts
            ah_src[r] = v ? (Ah + (size_t)srow * Dd + slot) : zp;
            al_src[r] = v ? (Al + (size_t)srow * Dd + slot) : zp;
            adst[r]   = (r * 4 + w) * 512;                    // shorts
        }
    }

    // ---- fragment read offsets ----
    int a_off[4];
#pragma unroll
    for (int i = 0; i < 4; ++i) {
        int rl = wm0 + i * 16 + ln;
        a_off[i] = ADMA ? (rl * 32 + (((lane >> 4) ^ ((rl >> 1) & 3)) << 3))
                        : (rl * 40 + (lane >> 4) * 8);
    }
    const int nlb    = wn0 + ln;
    const int b_off0 = BBASE + nlb * 32 +
                       (((lane >> 4) ^ ((nlb >> 1) & 3)) << 3);

    f32x4 acc[4][NJ];
#pragma unroll
    for (int i = 0; i < 4; ++i)
#pragma unroll
        for (int j = 0; j < NJ; ++j) acc[i][j] = (f32x4){0.f, 0.f, 0.f, 0.f};

    for (int kt = 0; kt < 32; ++kt) {
        __syncthreads();   // previous tile's ds_reads complete
        // ---- stage A ----
        if (ADMA) {
#pragma unroll
            for (int r = 0; r < 2; ++r) {
                dma16(ah_src[r] + kt * 32, &lds[adst[r]]);
                dma16(al_src[r] + kt * 32, &lds[APL + adst[r]]);
            }
        } else {
            const int k0 = kt * 32;
#pragma unroll
            for (int p = 0; p < 4; ++p) {
                float4 v = *reinterpret_cast<const float4*>(
                    &Af[(size_t)arow_src[p] * Dd + k0 + ac]);
                if (MODE == 1 && !avalid[p]) v = make_float4(0.f,0.f,0.f,0.f);
                int wo = (p * 32 + ar) * 40 + ac;
                unsigned short h0 = f2bf_rne(v.x), h1 = f2bf_rne(v.y),
                               h2 = f2bf_rne(v.z), h3 = f2bf_rne(v.w);
                unsigned short g0 = f2bf_rne(v.x - bf2f(h0)),
                               g1 = f2bf_rne(v.y - bf2f(h1)),
                               g2 = f2bf_rne(v.z - bf2f(h2)),
                               g3 = f2bf_rne(v.w - bf2f(h3));
                uint2 hw, lw;
                hw.x = (unsigned)h0 | ((unsigned)h1 << 16);
                hw.y = (unsigned)h2 | ((unsigned)h3 << 16);
                lw.x = (unsigned)g0 | ((unsigned)g1 << 16);
                lw.y = (unsigned)g2 | ((unsigned)g3 << 16);
                *reinterpret_cast<uint2*>(&lds[wo])       = hw;
                *reinterpret_cast<uint2*>(&lds[wo + APL]) = lw;
            }
        }
        // ---- stage B: async DMA from pre-swizzled split_bt layout ----
#pragma unroll
        for (int q = 0; q < NT / 64; ++q) {
            size_t gfo = ((size_t)(kt * 1024 + n0 + q * 64 + (tid >> 2))
                          * 4 + (tid & 3)) * 8;
            dma16(&Bth[gfo], &lds[BBASE + q * 2048 + w * 512]);
            dma16(&Btl[gfo], &lds[BBASE + BPL + q * 2048 + w * 512]);
        }
        __syncthreads();   // drains vmcnt (DMA) + lgkm (A writes)
        // ---- compute ----
        bf16x8 ah[4], al[4];
#pragma unroll
        for (int i = 0; i < 4; ++i) {
            ah[i] = *reinterpret_cast<const bf16x8*>(&lds[a_off[i]]);
            al[i] = *reinterpret_cast<const bf16x8*>(&lds[a_off[i] + APL]);
        }
#pragma unroll
        for (int j = 0; j < NJ; ++j) {
            const bf16x8 bh = *reinterpret_cast<const bf16x8*>(
                &lds[b_off0 + j * 512]);
            const bf16x8 bl = *reinterpret_cast<const bf16x8*>(
                &lds[b_off0 + j * 512 + BPL]);
#pragma unroll
            for (int i = 0; i < 4; ++i) {
                acc[i][j] = __builtin_amdgcn_mfma_f32_16x16x32_bf16(
                    ah[i], bh, acc[i][j], 0, 0, 0);
                acc[i][j] = __builtin_amdgcn_mfma_f32_16x16x32_bf16(
                    ah[i], bl, acc[i][j], 0, 0, 0);
                acc[i][j] = __builtin_amdgcn_mfma_f32_16x16x32_bf16(
                    al[i], bh, acc[i][j], 0, 0, 0);
            }
        }
    }

    // ---- epilogue ----
    float* bnF = reinterpret_cast<float*>(lds);
    if (BN) {
        __syncthreads();               // all LDS reads done; reuse as floats
        bnF[tid] = 0.f; bnF[256 + tid] = 0.f;
        __syncthreads();
    }
#pragma unroll
    for (int j = 0; j < NJ; ++j) {
        int cl  = wn0 + j * 16 + ln;
        int col = n0 + cl;
        float bj = (MODE == 0 && bias) ? bias[col] : 0.f;
        float sv = 0.f, sq = 0.f;
#pragma unroll
        for (int i = 0; i < 4; ++i) {
            int rbase = m0g + wm0 + i * 16 + (lane >> 4) * 4;
#pragma unroll
            for (int e = 0; e < 4; ++e) {
                size_t off = (size_t)(rbase + e) * Dd + col;
                float v = acc[i][j][e] + bj;
                if (MODE >= 1)
                    v += rec2((unsigned short)Sh[off], (unsigned short)Sl[off]);
                if (OSPLIT) {
                    unsigned short hs = f2bf_rne(v);
                    unsigned short ls = f2bf_rne(v - bf2f(hs));
                    Ch[off] = (short)hs;
                    Cl[off] = (short)ls;
                } else {
                    Cf[off] = v;
                }
                if (BN) { sv += v; sq += v * v; }
            }
        }
        if (BN) { atomicAdd(&bnF[cl], sv); atomicAdd(&bnF[256 + cl], sq); }
    }
    if (BN) {
        __syncthreads();
        psum[(size_t)blockIdx.y * Dd + n0 + tid] = bnF[tid];
        psq [(size_t)blockIdx.y * Dd + n0 + tid] = bnF[256 + tid];
    }
}

// ---------------------------------------------------------------------------
__global__ __launch_bounds__(256)
void bn_stats(const float* __restrict__ ps, const float* __restrict__ pq,
              const float* __restrict__ scale, const float* __restrict__ bias,
              float* __restrict__ Av, float* __restrict__ Cv)
{
    const int d = blockIdx.x * 256 + threadIdx.x;
    float s = 0.f, q = 0.f;
    for (int p = 0; p < 256; ++p) {
        s += ps[p * Dd + d];
        q += pq[p * Dd + d];
    }
    const float invN = 1.0f / 32768.0f;
    float mean = s * invN;
    float var  = q * invN - mean * mean;
    float rs   = rsqrtf(var + 1e-5f);
    float a    = rs * scale[d];
    Av[d] = a;
    Cv[d] = bias[d] - mean * a;
}

// ---------------------------------------------------------------------------
// y_out = gelu(z*a+c) + y, all states dual-plane bf16; LAST=1 writes fp32 out.
// ---------------------------------------------------------------------------
template<int LAST>
__global__ __launch_bounds__(256)
void residual_gelu(const short* __restrict__ Zh, const short* __restrict__ Zl,
                   const short* __restrict__ Yh, const short* __restrict__ Yl,
                   short* __restrict__ Oh, short* __restrict__ Ol,
                   float* __restrict__ Of,
                   const float* __restrict__ Av, const float* __restrict__ Cv)
{
    const int ng = MTOT * Dd / 8;
    for (int g = blockIdx.x * blockDim.x + threadIdx.x; g < ng;
         g += gridDim.x * blockDim.x) {
        size_t base = (size_t)g * 8;
        int d0 = (int)(base & (Dd - 1));
        bf16x8 zh = *reinterpret_cast<const bf16x8*>(&Zh[base]);
        bf16x8 zl = *reinterpret_cast<const bf16x8*>(&Zl[base]);
        bf16x8 yh = *reinterpret_cast<const bf16x8*>(&Yh[base]);
        bf16x8 yl = *reinterpret_cast<const bf16x8*>(&Yl[base]);
        float4 a0 = *reinterpret_cast<const float4*>(&Av[d0]);
        float4 a1 = *reinterpret_cast<const float4*>(&Av[d0 + 4]);
        float4 c0 = *reinterpret_cast<const float4*>(&Cv[d0]);
        float4 c1 = *reinterpret_cast<const float4*>(&Cv[d0 + 4]);
        float av[8] = {a0.x,a0.y,a0.z,a0.w,a1.x,a1.y,a1.z,a1.w};
        float cw[8] = {c0.x,c0.y,c0.z,c0.w,c1.x,c1.y,c1.z,c1.w};
        float o[8];
#pragma unroll
        for (int e = 0; e < 8; ++e) {
            float z = rec2((unsigned short)zh[e], (unsigned short)zl[e]);
            float y = rec2((unsigned short)yh[e], (unsigned short)yl[e]);
            o[e] = gelu_tanh(fmaf(z, av[e], cw[e])) + y;
        }
        if (LAST) {
            float4 o0 = {o[0], o[1], o[2], o[3]};
            float4 o1 = {o[4], o[5], o[6], o[7]};
            *reinterpret_cast<float4*>(&Of[base])     = o0;
            *reinterpret_cast<float4*>(&Of[base + 4]) = o1;
        } else {
            bf16x8 oh, ol;
#pragma unroll
            for (int e = 0; e < 8; ++e) {
                unsigned short hs = f2bf_rne(o[e]);
                oh[e] = (short)hs;
                ol[e] = (short)f2bf_rne(o[e] - bf2f(hs));
            }
            *reinterpret_cast<bf16x8*>(&Oh[base]) = oh;
            *reinterpret_cast<bf16x8*>(&Ol[base]) = ol;
        }
    }
}

// ---------------------------------------------------------------------------
extern "C" void kernel_launch(void* const* d_in, const int* in_sizes, int n_in,
                              void* d_out, int out_size, void* d_ws, size_t ws_size,
                              hipStream_t stream)
{
    const float* x    = (const float*)d_in[0];
    const float* Wi   = (const float*)d_in[1];
    const float* bi   = (const float*)d_in[2];
    const float* Wh   = (const float*)d_in[3];
    const float* mlpW = (const float*)d_in[4];
    const float* mlpb = (const float*)d_in[5];
    const float* bns  = (const float*)d_in[6];
    const float* bnb  = (const float*)d_in[7];
    float* out = (float*)d_out;

    const size_t NE = (size_t)MTOT * Dd;     // 33,554,432
    short* S0h = (short*)d_ws;               // state 0 planes
    short* S0l = S0h + NE;
    short* S1h = S0l + NE;                   // state 1 planes
    short* S1l = S1h + NE;
    float* Pa  = (float*)(S1l + NE);         // power matrices fp32
    float* Pb  = Pa + (size_t)Dd * Dd;
    float* psum = Pb + (size_t)Dd * Dd;      // [256][1024]
    float* psq  = psum + 256 * Dd;
    float* abuf = psq + 256 * Dd;
    float* cbuf = abuf + Dd;
    short* Bth  = (short*)(cbuf + Dd);       // split B (1M shorts each)
    short* Btl  = Bth + (size_t)Dd * Dd;
    short* zp   = Btl + (size_t)Dd * Dd;     // 4 KB zero page

    const dim3 gBig(4, 256);    // 128x256 tiles
    const dim3 gSq (8, 8);      // 128x128 tiles
    const dim3 gSeq(8, 16);
    const dim3 gBt (32, 32);

    hipMemsetAsync(zp, 0, 8192, stream);

#define SPLIT(M) split_bt<<<gBt, 256, 0, stream>>>((M), Bth, Btl)
    // scan level: A/Sin = state planes (src), out = state planes (dst)
#define LEVEL(srcH, srcL, dstH, dstL, m_)                                     \
    mfma_gemm<1, 0, 256, 1, 1><<<gBig, 256, 0, stream>>>(                     \
        nullptr, (srcH), (srcL), Bth, Btl, nullptr, (srcH), (srcL),           \
        nullptr, (dstH), (dstL), nullptr, nullptr, zp, (m_), 0)
    // power squaring: fp32 A, fp32 out
#define SQUARE(Afp, Cfp)                                                      \
    mfma_gemm<0, 0, 128, 0, 0><<<gSq, 256, 0, stream>>>(                      \
        (Afp), nullptr, nullptr, Bth, Btl, nullptr, nullptr, nullptr,         \
        (Cfp), nullptr, nullptr, nullptr, nullptr, zp, 0, 0)

    // Phase 1: xp = x @ Wi + bi -> state0 (hi/lo)
    SPLIT(Wi);
    mfma_gemm<0, 0, 256, 0, 1><<<gBig, 256, 0, stream>>>(
        x, nullptr, nullptr, Bth, Btl, bi, nullptr, nullptr,
        nullptr, S0h, S0l, nullptr, nullptr, zp, 0, 0);

    // Phase 2: 7 scan-doubling levels (window 128), powers interleaved.
    SPLIT(Wh);
    LEVEL(S0h, S0l, S1h, S1l, 1);            // L1
    SQUARE(Wh, Pa);                          // P2
    SPLIT(Pa);
    LEVEL(S1h, S1l, S0h, S0l, 2);            // L2
    SQUARE(Pa, Pb);                          // P4
    SPLIT(Pb);
    LEVEL(S0h, S0l, S1h, S1l, 4);            // L3
    SQUARE(Pb, Pa);                          // P8
    SPLIT(Pa);
    LEVEL(S1h, S1l, S0h, S0l, 8);            // L4
    SQUARE(Pa, Pb);                          // P16
    SPLIT(Pb);
    LEVEL(S0h, S0l, S1h, S1l, 16);           // L5
    SQUARE(Pb, Pa);                          // P32
    SPLIT(Pa);
    LEVEL(S1h, S1l, S0h, S0l, 32);           // L6
    SQUARE(Pa, Pb);                          // P64
    SPLIT(Pb);
    LEVEL(S0h, S0l, S1h, S1l, 64);           // L7 -> state1
    SQUARE(Pb, Pa);                          // P128
    SPLIT(Pa);

    // Phase 3: 15 sequential carry steps with P128 (in-place on state1)
    for (int i = 1; i < 16; ++i)
        mfma_gemm<2, 0, 128, 1, 1><<<gSeq, 256, 0, stream>>>(
            nullptr, S1h, S1l, Bth, Btl, nullptr, S1h, S1l,
            nullptr, S1h, S1l, nullptr, nullptr, zp, 128, 128 * i);

    // Phase 4: residual MLP stack; y in state1, z -> state0
    for (int l = 0; l < NL; ++l) {
        SPLIT(mlpW + (size_t)l * Dd * Dd);
        mfma_gemm<0, 1, 256, 1, 1><<<gBig, 256, 0, stream>>>(
            nullptr, S1h, S1l, Bth, Btl, mlpb + (size_t)l * Dd,
            nullptr, nullptr, nullptr, S0h, S0l, psum, psq, zp, 0, 0);
        bn_stats<<<4, 256, 0, stream>>>(psum, psq, bns + (size_t)l * Dd,
                                        bnb + (size_t)l * Dd, abuf, cbuf);
        if (l < NL - 1)
            residual_gelu<0><<<2048, 256, 0, stream>>>(
                S0h, S0l, S1h, S1l, S1h, S1l, nullptr, abuf, cbuf);
        else
            residual_gelu<1><<<2048, 256, 0, stream>>>(
                S0h, S0l, S1h, S1l, nullptr, nullptr, out, abuf, cbuf);
    }
#undef SPLIT
#undef LEVEL
#undef SQUARE
}

// Round 11
// 3751.191 us; speedup vs baseline: 1.2521x; 1.2521x over previous
//
#include <hip/hip_runtime.h>
#include <math.h>

#define Bb   16
#define Tt   2048
#define Dd   1024
#define NL   4
#define MTOT (Bb * Tt)   // 32768

typedef float f32x4 __attribute__((ext_vector_type(4)));
typedef short bf16x8 __attribute__((ext_vector_type(8)));

// ---------------------------------------------------------------------------
__device__ __forceinline__ unsigned short f2bf_rne(float x) {
    unsigned u = __float_as_uint(x);
    u += 0x7fffu + ((u >> 16) & 1u);
    return (unsigned short)(u >> 16);
}
__device__ __forceinline__ float bf2f(unsigned short h) {
    return __uint_as_float(((unsigned)h) << 16);
}
__device__ __forceinline__ float gelu_tanh(float x) {
    float x3 = x * x * x;
    float u  = 0.7978845608028654f * (x + 0.044715f * x3);
    return 0.5f * x * (1.0f + tanhf(u));
}
// async 16B global -> LDS (HW: wave-uniform LDS base + lane*16)
__device__ __forceinline__ void dma16(const void* g, void* l) {
    __builtin_amdgcn_global_load_lds(
        (const __attribute__((address_space(1))) unsigned int*)g,
        (__attribute__((address_space(3))) unsigned int*)l, 16, 0, 0);
}

// ---------------------------------------------------------------------------
// Split a [1024,1024] fp32 matrix (row-major [k][n]) into bf16 hi/lo with
// k-tiled, slot-swizzled layout (proven R6 B-path):
//   element (k,n): kt=k>>5, sl=(k>>3)&3, e=k&7
//   shorts offset = ((kt*1024+n)*4 + (sl^((n>>1)&3)))*8 + e
// ---------------------------------------------------------------------------
__global__ __launch_bounds__(256)
void split_bt(const float* __restrict__ B, short* __restrict__ ht,
              short* __restrict__ lt)
{
    __shared__ float tile[32][33];
    const int t  = threadIdx.x;
    const int r  = t >> 3;          // 0..31
    const int c  = (t & 7) * 4;     // 0,4,...,28
    const int kb = blockIdx.y * 32; // kt = blockIdx.y
    const int nb = blockIdx.x * 32;
    float4 v = *reinterpret_cast<const float4*>(
        &B[(size_t)(kb + r) * Dd + nb + c]);
    tile[r][c + 0] = v.x; tile[r][c + 1] = v.y;
    tile[r][c + 2] = v.z; tile[r][c + 3] = v.w;
    __syncthreads();
    unsigned h[4], lo[4];
#pragma unroll
    for (int q = 0; q < 4; ++q) {
        float f = tile[c + q][r];           // B[kb+c+q][nb+r]
        unsigned short hh = f2bf_rne(f);
        float rem = f - bf2f(hh);
        h[q]  = hh;
        lo[q] = f2bf_rne(rem);
    }
    uint2 hw, lw;
    hw.x = h[0]  | (h[1]  << 16); hw.y = h[2]  | (h[3]  << 16);
    lw.x = lo[0] | (lo[1] << 16); lw.y = lo[2] | (lo[3] << 16);
    const int n = nb + r;
    const int s = (c >> 3) ^ ((n >> 1) & 3);   // swizzled slot
    size_t off = ((size_t)(blockIdx.y * 1024 + n) * 4 + s) * 8 + (c & 4);
    *reinterpret_cast<uint2*>(&ht[off]) = hw;
    *reinterpret_cast<uint2*>(&lt[off]) = lw;
}

// ---------------------------------------------------------------------------
// R6-proven split-precision MFMA GEMM body (device function, inlined).
// Tile 128xNT, BK=32, 256 thr = 4 waves (2x2), two barriers per k-tile,
// A fp32 reg->convert->ds_write, B via dma16 from pre-split layout.
// S3=1: split precision (hi+lo planes, 3 MFMA). S3=0: bf16 hi-only (1 MFMA).
// MODE 0: C = A@B (+bias); MODE 1: C[t]=Sin[t]+(t%Tt>=m ? A[t-m]@B : 0);
// MODE 2: rows [tstart,tstart+128) per batch: C[r]=Sin[r]+A[r-128]@B.
// BN=1: per-(m-tile,col) partial sum/sumsq via LDS (reused post-compute).
// WSPLIT=1: epilogue also writes C into the split/swizzled B-layout
//           (Woh/Wol) — used by power squarings to feed the next level.
// ---------------------------------------------------------------------------
template<int MODE, int BN, int NT, int S3, int WSPLIT>
__device__ __forceinline__ void gemm_body(
    short* lds, int bx, int by,
    const float* __restrict__ Af,
    const short* __restrict__ Bth, const short* __restrict__ Btl,
    const float* __restrict__ bias,
    const float* __restrict__ Sin,
    float* __restrict__ Cf,
    short* __restrict__ Woh, short* __restrict__ Wol,
    float* __restrict__ psum, float* __restrict__ psq,
    int m, int tstart)
{
    constexpr int NJ    = NT / 32;
    constexpr int APL   = 5120;              // shorts per A plane (128*40)
    constexpr int BBASE = (S3 ? 2 : 1) * APL;
    constexpr int BPL   = NT * 32;           // shorts per B plane

    const int tid  = threadIdx.x;
    const int lane = tid & 63;
    const int w    = tid >> 6;
    const int n0   = bx * NT;
    const int m0g  = (MODE == 2) ? (by * Tt + tstart) : (by * 128);
    const int wm0  = (w >> 1) * 64;
    const int wn0  = (w & 1) * (NT / 2);
    const int ln   = lane & 15;
    const int ar   = tid >> 3;
    const int ac   = (tid & 7) * 4;

    int  arow_src[4]; bool avalid[4];
#pragma unroll
    for (int p = 0; p < 4; ++p) {
        int rg = m0g + p * 32 + ar;
        bool v = true;
        if (MODE == 1) v = ((rg & (Tt - 1)) >= m);
        avalid[p]   = v;
        arow_src[p] = (MODE >= 1 && v) ? (rg - m) : rg;
    }

    f32x4 acc[4][NJ];
#pragma unroll
    for (int i = 0; i < 4; ++i)
#pragma unroll
        for (int j = 0; j < NJ; ++j) acc[i][j] = (f32x4){0.f, 0.f, 0.f, 0.f};

    int a_off[4];
#pragma unroll
    for (int i = 0; i < 4; ++i)
        a_off[i] = (wm0 + i * 16 + ln) * 40 + (lane >> 4) * 8;
    const int nlb    = wn0 + ln;
    const int b_off0 = BBASE + nlb * 32 +
                       (((lane >> 4) ^ ((nlb >> 1) & 3)) << 3);

    for (int kt = 0; kt < 32; ++kt) {
        __syncthreads();   // previous tile's ds_reads complete
        // ---- stage A: global fp32 -> bf16 (hi [+lo]) -> LDS ----
#pragma unroll
        for (int p = 0; p < 4; ++p) {
            float4 v = *reinterpret_cast<const float4*>(
                &Af[(size_t)arow_src[p] * Dd + kt * 32 + ac]);
            if (MODE == 1 && !avalid[p]) v = make_float4(0.f, 0.f, 0.f, 0.f);
            int wo = (p * 32 + ar) * 40 + ac;
            unsigned short h0 = f2bf_rne(v.x), h1 = f2bf_rne(v.y),
                           h2 = f2bf_rne(v.z), h3 = f2bf_rne(v.w);
            uint2 hw;
            hw.x = (unsigned)h0 | ((unsigned)h1 << 16);
            hw.y = (unsigned)h2 | ((unsigned)h3 << 16);
            *reinterpret_cast<uint2*>(&lds[wo]) = hw;
            if (S3) {
                unsigned short g0 = f2bf_rne(v.x - bf2f(h0)),
                               g1 = f2bf_rne(v.y - bf2f(h1)),
                               g2 = f2bf_rne(v.z - bf2f(h2)),
                               g3 = f2bf_rne(v.w - bf2f(h3));
                uint2 lw;
                lw.x = (unsigned)g0 | ((unsigned)g1 << 16);
                lw.y = (unsigned)g2 | ((unsigned)g3 << 16);
                *reinterpret_cast<uint2*>(&lds[wo + APL]) = lw;
            }
        }
        // ---- stage B: async DMA from pre-split swizzled layout ----
#pragma unroll
        for (int q = 0; q < NT / 64; ++q) {
            size_t gfo = ((size_t)(kt * 1024 + n0 + q * 64 + (tid >> 2))
                          * 4 + (tid & 3)) * 8;
            dma16(&Bth[gfo], &lds[BBASE + q * 2048 + w * 512]);
            if (S3)
                dma16(&Btl[gfo], &lds[BBASE + BPL + q * 2048 + w * 512]);
        }
        __syncthreads();   // drains vmcnt (DMA) + lgkm (A writes)
        // ---- compute ----
        bf16x8 ah[4], al[4];
#pragma unroll
        for (int i = 0; i < 4; ++i) {
            ah[i] = *reinterpret_cast<const bf16x8*>(&lds[a_off[i]]);
            if (S3)
                al[i] = *reinterpret_cast<const bf16x8*>(&lds[a_off[i] + APL]);
        }
#pragma unroll
        for (int j = 0; j < NJ; ++j) {
            const bf16x8 bh = *reinterpret_cast<const bf16x8*>(
                &lds[b_off0 + j * 512]);
#pragma unroll
            for (int i = 0; i < 4; ++i)
                acc[i][j] = __builtin_amdgcn_mfma_f32_16x16x32_bf16(
                    ah[i], bh, acc[i][j], 0, 0, 0);
            if (S3) {
                const bf16x8 bl = *reinterpret_cast<const bf16x8*>(
                    &lds[b_off0 + j * 512 + BPL]);
#pragma unroll
                for (int i = 0; i < 4; ++i) {
                    acc[i][j] = __builtin_amdgcn_mfma_f32_16x16x32_bf16(
                        ah[i], bl, acc[i][j], 0, 0, 0);
                    acc[i][j] = __builtin_amdgcn_mfma_f32_16x16x32_bf16(
                        al[i], bh, acc[i][j], 0, 0, 0);
                }
            }
        }
    }

    // ---- epilogue ----
    float* bnF = reinterpret_cast<float*>(lds);
    if (BN) {
        __syncthreads();               // all LDS reads done; reuse as floats
        bnF[tid] = 0.f; bnF[256 + tid] = 0.f;
        __syncthreads();
    }
#pragma unroll
    for (int j = 0; j < NJ; ++j) {
        int cl  = wn0 + j * 16 + ln;
        int col = n0 + cl;
        float bj = (MODE == 0 && bias) ? bias[col] : 0.f;
        float sv = 0.f, sq = 0.f;
#pragma unroll
        for (int i = 0; i < 4; ++i) {
            int rbase = m0g + wm0 + i * 16 + (lane >> 4) * 4;
            float vv[4];
#pragma unroll
            for (int e = 0; e < 4; ++e) {
                size_t off = (size_t)(rbase + e) * Dd + col;
                float v = acc[i][j][e] + bj;
                if (MODE >= 1) v += Sin[off];
                Cf[off] = v;
                vv[e] = v;
                if (BN) { sv += v; sq += v * v; }
            }
            if (WSPLIT) {
                // write into split/swizzled B-layout: row index = k dim
                unsigned short h0 = f2bf_rne(vv[0]), h1 = f2bf_rne(vv[1]),
                               h2 = f2bf_rne(vv[2]), h3 = f2bf_rne(vv[3]);
                unsigned short l0 = f2bf_rne(vv[0] - bf2f(h0)),
                               l1 = f2bf_rne(vv[1] - bf2f(h1)),
                               l2 = f2bf_rne(vv[2] - bf2f(h2)),
                               l3 = f2bf_rne(vv[3] - bf2f(h3));
                uint2 hw, lw;
                hw.x = (unsigned)h0 | ((unsigned)h1 << 16);
                hw.y = (unsigned)h2 | ((unsigned)h3 << 16);
                lw.x = (unsigned)l0 | ((unsigned)l1 << 16);
                lw.y = (unsigned)l2 | ((unsigned)l3 << 16);
                int kt2 = rbase >> 5;
                int sl  = (rbase >> 3) & 3;
                int e0  = rbase & 7;                 // 0 or 4
                size_t so = ((size_t)(kt2 * 1024 + col) * 4 +
                             (sl ^ ((col >> 1) & 3))) * 8 + e0;
                *reinterpret_cast<uint2*>(&Woh[so]) = hw;
                *reinterpret_cast<uint2*>(&Wol[so]) = lw;
            }
        }
        if (BN) { atomicAdd(&bnF[cl], sv); atomicAdd(&bnF[256 + cl], sq); }
    }
    if (BN) {
        __syncthreads();
        psum[(size_t)by * Dd + n0 + tid] = bnF[tid];
        psq [(size_t)by * Dd + n0 + tid] = bnF[256 + tid];
    }
}

// ---------------------------------------------------------------------------
template<int MODE, int BN, int NT, int S3>
__global__ __launch_bounds__(256, 2)
void mfma_gemm(const float* __restrict__ Af,
               const short* __restrict__ Bth, const short* __restrict__ Btl,
               const float* __restrict__ bias,
               const float* __restrict__ Sin,
               float* __restrict__ Cf,
               float* __restrict__ psum, float* __restrict__ psq,
               int m, int tstart)
{
    constexpr int LSZ = (S3 ? 2 : 1) * (5120 + NT * 32);
    __shared__ __align__(16) short lds[LSZ];
    gemm_body<MODE, BN, NT, S3, 0>(lds, blockIdx.x, blockIdx.y,
                                   Af, Bth, Btl, bias, Sin, Cf,
                                   nullptr, nullptr, psum, psq, m, tstart);
}

// ---------------------------------------------------------------------------
// Fused [scan level (1024 blocks, NT=256) + power squaring (64 blocks,
// NT=128, WSPLIT)] launch. Squares occupy by<16 (dispatch first), levels
// by in [16, 272). Both paths share one 52 KB LDS block; 2 blocks/CU.
// ---------------------------------------------------------------------------
__global__ __launch_bounds__(256, 2)
void fused_ls(const float* __restrict__ Sfrom, float* __restrict__ Sto,
              const float* __restrict__ Pfrom, float* __restrict__ Pto,
              const short* __restrict__ Bqh, const short* __restrict__ Bql,
              short* __restrict__ Bqoh, short* __restrict__ Bqol,
              int m)
{
    __shared__ __align__(16) short lds[2 * (5120 + 8192)];
    if (blockIdx.y < 16) {
        int sq  = blockIdx.y;
        int sbx = blockIdx.x + ((sq & 1) << 2);   // 0..7
        int sby = sq >> 1;                        // 0..7
        gemm_body<0, 0, 128, 1, 1>(lds, sbx, sby, Pfrom, Bqh, Bql,
                                   nullptr, nullptr, Pto, Bqoh, Bqol,
                                   nullptr, nullptr, 0, 0);
    } else {
        gemm_body<1, 0, 256, 1, 0>(lds, blockIdx.x, blockIdx.y - 16,
                                   Sfrom, Bqh, Bql, nullptr, Sfrom, Sto,
                                   nullptr, nullptr, nullptr, nullptr, m, 0);
    }
}

// ---------------------------------------------------------------------------
__global__ __launch_bounds__(256)
void bn_stats(const float* __restrict__ ps, const float* __restrict__ pq,
              const float* __restrict__ scale, const float* __restrict__ bias,
              float* __restrict__ Av, float* __restrict__ Cv)
{
    const int d = blockIdx.x * 256 + threadIdx.x;
    float s = 0.f, q = 0.f;
    for (int p = 0; p < 256; ++p) {
        s += ps[p * Dd + d];
        q += pq[p * Dd + d];
    }
    const float invN = 1.0f / 32768.0f;
    float mean = s * invN;
    float var  = q * invN - mean * mean;
    float rs   = rsqrtf(var + 1e-5f);
    float a    = rs * scale[d];
    Av[d] = a;
    Cv[d] = bias[d] - mean * a;
}

// ---------------------------------------------------------------------------
__global__ __launch_bounds__(256)
void residual_gelu(const float* __restrict__ Z, const float* __restrict__ Yin,
                   float* __restrict__ Yout,
                   const float* __restrict__ Av, const float* __restrict__ Cv)
{
    const float4* z4 = reinterpret_cast<const float4*>(Z);
    const float4* y4 = reinterpret_cast<const float4*>(Yin);
    float4*       o4 = reinterpret_cast<float4*>(Yout);
    const float4* a4 = reinterpret_cast<const float4*>(Av);
    const float4* c4 = reinterpret_cast<const float4*>(Cv);
    const int n4 = MTOT * Dd / 4;
    for (int i = blockIdx.x * blockDim.x + threadIdx.x; i < n4;
         i += gridDim.x * blockDim.x) {
        int d4 = i & (Dd / 4 - 1);
        float4 z = z4[i], y = y4[i], a = a4[d4], c = c4[d4];
        float4 o;
        o.x = gelu_tanh(fmaf(z.x, a.x, c.x)) + y.x;
        o.y = gelu_tanh(fmaf(z.y, a.y, c.y)) + y.y;
        o.z = gelu_tanh(fmaf(z.z, a.z, c.z)) + y.z;
        o.w = gelu_tanh(fmaf(z.w, a.w, c.w)) + y.w;
        o4[i] = o;
    }
}

// ---------------------------------------------------------------------------
extern "C" void kernel_launch(void* const* d_in, const int* in_sizes, int n_in,
                              void* d_out, int out_size, void* d_ws, size_t ws_size,
                              hipStream_t stream)
{
    const float* x    = (const float*)d_in[0];
    const float* Wi   = (const float*)d_in[1];
    const float* bi   = (const float*)d_in[2];
    const float* Wh   = (const float*)d_in[3];
    const float* mlpW = (const float*)d_in[4];
    const float* mlpb = (const float*)d_in[5];
    const float* bns  = (const float*)d_in[6];
    const float* bnb  = (const float*)d_in[7];
    float* out = (float*)d_out;

    const size_t NE = (size_t)MTOT * Dd;
    const size_t MM = (size_t)Dd * Dd;       // 1M
    float* ws   = (float*)d_ws;
    float* S0   = ws;                        // 32M floats (128 MiB)
    float* Pa   = S0 + NE;
    float* Pb   = Pa + MM;
    float* psum = Pb + MM;                   // [256][1024]
    float* psq  = psum + 256 * Dd;
    float* abuf = psq + 256 * Dd;
    float* cbuf = abuf + Dd;
    short* Bq0h = (short*)(cbuf + Dd);       // 6 split buffers, 2M shorts each
    short* Bq0l = Bq0h + MM;
    short* Bq1h = Bq0l + MM;
    short* Bq1l = Bq1h + MM;
    short* BmH[NL]; short* BmL[NL];
    {
        short* p = Bq1l + MM;
        for (int l = 0; l < NL; ++l) { BmH[l] = p; p += MM; BmL[l] = p; p += MM; }
    }

    const dim3 gBig(4, 256);    // 128x256 tiles
    const dim3 gF  (4, 272);    // fused: 16 square-rows + 256 level-rows
    const dim3 gSeq(8, 16);     // carries: 128x128 tiles
    const dim3 gBt (32, 32);

    // ---- all input-matrix splits upfront ----
    split_bt<<<gBt, 256, 0, stream>>>(Wi, Bq0h, Bq0l);
    split_bt<<<gBt, 256, 0, stream>>>(Wh, Bq1h, Bq1l);
    for (int l = 0; l < NL; ++l)
        split_bt<<<gBt, 256, 0, stream>>>(mlpW + (size_t)l * MM, BmH[l], BmL[l]);

    // ---- Phase 1: xp = x @ Wi + bi -> S0 ----
    mfma_gemm<0, 0, 256, 1><<<gBig, 256, 0, stream>>>(
        x, Bq0h, Bq0l, bi, nullptr, S0, nullptr, nullptr, 0, 0);

    // ---- Phase 2: 7 fused [level + squaring] launches ----
    // F_k: level m=2^(k-1) with B=split(P_{2^(k-1)}); square P->P^2 into the
    // other fp32 buffer + the other split buffer.
    fused_ls<<<gF, 256, 0, stream>>>(S0, out, Wh, Pa, Bq1h, Bq1l, Bq0h, Bq0l, 1);
    fused_ls<<<gF, 256, 0, stream>>>(out, S0, Pa, Pb, Bq0h, Bq0l, Bq1h, Bq1l, 2);
    fused_ls<<<gF, 256, 0, stream>>>(S0, out, Pb, Pa, Bq1h, Bq1l, Bq0h, Bq0l, 4);
    fused_ls<<<gF, 256, 0, stream>>>(out, S0, Pa, Pb, Bq0h, Bq0l, Bq1h, Bq1l, 8);
    fused_ls<<<gF, 256, 0, stream>>>(S0, out, Pb, Pa, Bq1h, Bq1l, Bq0h, Bq0l, 16);
    fused_ls<<<gF, 256, 0, stream>>>(out, S0, Pa, Pb, Bq0h, Bq0l, Bq1h, Bq1l, 32);
    fused_ls<<<gF, 256, 0, stream>>>(S0, out, Pb, Pa, Bq1h, Bq1l, Bq0h, Bq0l, 64);
    // state now in `out`; split(P128) now in Bq0.

    // ---- Phase 3: 15 sequential carry steps with P128 (in-place on out) ----
    for (int i = 1; i < 16; ++i)
        mfma_gemm<2, 0, 128, 1><<<gSeq, 256, 0, stream>>>(
            out, Bq0h, Bq0l, nullptr, out, out, nullptr, nullptr, 128, 128 * i);

    // ---- Phase 4: residual MLP stack (plain-bf16 GEMMs); y in out, z -> S0 ----
    for (int l = 0; l < NL; ++l) {
        mfma_gemm<0, 1, 256, 0><<<gBig, 256, 0, stream>>>(
            out, BmH[l], BmL[l], mlpb + (size_t)l * Dd, nullptr, S0,
            psum, psq, 0, 0);
        bn_stats<<<4, 256, 0, stream>>>(psum, psq, bns + (size_t)l * Dd,
                                        bnb + (size_t)l * Dd, abuf, cbuf);
        residual_gelu<<<2048, 256, 0, stream>>>(S0, out, out, abuf, cbuf);
    }
}